// Round 5
// baseline (280.094 us; speedup 1.0000x reference)
//
#include <hip/hip_runtime.h>
#include <hip/hip_bf16.h>
#include <cmath>

#define DEV __device__ __forceinline__

typedef float  f32x4  __attribute__((ext_vector_type(4)));
typedef __bf16 bf16x8 __attribute__((ext_vector_type(8)));
using u16 = unsigned short;
using u32 = unsigned int;

constexpr int CB   = 2;     // batch
constexpr int CLEN = 1024;  // seq len
constexpr int CDM  = 1024;  // d_model
constexpr int CDI  = 2048;  // d_inner
constexpr int CM   = CB * CLEN;  // 2048 GEMM rows
constexpr int NCHUNK = 32;  // scan chunks
constexpr int CHL    = 32;  // chunk length

DEV u16 f2bf(float f) {
  unsigned u = __builtin_bit_cast(unsigned, f);
  unsigned r = (u + 0x7fffu + ((u >> 16) & 1u)) >> 16;  // RNE
  return (u16)r;
}
DEV float bf2f(u16 v) { return __builtin_bit_cast(float, ((unsigned)v) << 16); }

DEV ushort4 f4bf(float4 v) {
  ushort4 o;
  o.x = f2bf(v.x); o.y = f2bf(v.y); o.z = f2bf(v.z); o.w = f2bf(v.w);
  return o;
}

// ------------------------------------------------------------------
// fused cast kernel: x, W_in, W_dt, W_out, W_x(pad 96->128) -> bf16
// + zero-init of the two fp32 atomic accumulators (out, xdbl)
// ------------------------------------------------------------------
constexpr int CG_X   = 524288;                 // 2048*1024/4
constexpr int CG_WIN = CG_X   + 1048576;       // 4096*1024/4
constexpr int CG_WDT = CG_WIN + 32768;         // 2048*64/4
constexpr int CG_WO  = CG_WDT + 524288;        // 1024*2048/4
constexpr int CG_WX  = CG_WO  + 65536;         // 128*2048/4 (padded out)
constexpr int CG_ZO  = CG_WX  + 524288;        // zero out (2048*1024/4)
constexpr int CG_ZX  = CG_ZO  + 65536;         // zero xdbl (2048*128/4)

__global__ void cast_all_k(const float* __restrict__ x, const float* __restrict__ W_in,
                           const float* __restrict__ W_dt, const float* __restrict__ W_out,
                           const float* __restrict__ W_x,
                           u16* __restrict__ xb, u16* __restrict__ W_inb,
                           u16* __restrict__ W_dtb, u16* __restrict__ W_outb,
                           u16* __restrict__ W_xb,
                           float* __restrict__ out_z, float* __restrict__ xdbl_z)
{
  int i = blockIdx.x * blockDim.x + threadIdx.x;
  if (i < CG_X) {
    reinterpret_cast<ushort4*>(xb)[i] = f4bf(reinterpret_cast<const float4*>(x)[i]);
  } else if (i < CG_WIN) {
    int j = i - CG_X;
    reinterpret_cast<ushort4*>(W_inb)[j] = f4bf(reinterpret_cast<const float4*>(W_in)[j]);
  } else if (i < CG_WDT) {
    int j = i - CG_WIN;
    reinterpret_cast<ushort4*>(W_dtb)[j] = f4bf(reinterpret_cast<const float4*>(W_dt)[j]);
  } else if (i < CG_WO) {
    int j = i - CG_WDT;
    reinterpret_cast<ushort4*>(W_outb)[j] = f4bf(reinterpret_cast<const float4*>(W_out)[j]);
  } else if (i < CG_WX) {
    int j = i - CG_WO;
    int base = j * 4, row = base >> 11, col = base & 2047;
    float4 v = make_float4(0.f, 0.f, 0.f, 0.f);
    if (row < 96) v = *reinterpret_cast<const float4*>(W_x + row * 2048 + col);
    reinterpret_cast<ushort4*>(W_xb)[j] = f4bf(v);
  } else if (i < CG_ZO) {
    reinterpret_cast<float4*>(out_z)[i - CG_WX] = make_float4(0.f, 0.f, 0.f, 0.f);
  } else {
    reinterpret_cast<float4*>(xdbl_z)[i - CG_ZO] = make_float4(0.f, 0.f, 0.f, 0.f);
  }
}

// ------------------------------------------------------------------
// bf16 MFMA GEMM, NT layout: C[M][N] = A[M][K] * B[N][K]^T
// 128x128 tile, BK=32, 4 waves each computing 64x64 (4x4 MFMA tiles)
// EPI: 0 = fp32 store; 1 = bf16 store; 3 = softplus(acc+bias)->bf16 @ stride2
//      4 = fp32 atomic-add into C (split-K accumulation)
// ------------------------------------------------------------------
DEV void gload_lds16(const void* g, void* l) {
  __builtin_amdgcn_global_load_lds(
      (const __attribute__((address_space(1))) void*)g,
      (__attribute__((address_space(3))) void*)l, 16, 0, 0);
}

template <int EPI, int SPLITK>
__global__ __launch_bounds__(256, 2)
void gemm_bt(const u16* __restrict__ A, const u16* __restrict__ Bw,
             float* __restrict__ C, u16* __restrict__ Cb,
             const float* __restrict__ bias,
             int Nd, int Kd, int lda, int ldb, int ldc)
{
  __shared__ u16 As[128 * 32];
  __shared__ u16 Bs[128 * 32];
  const int tid  = threadIdx.x;
  const int wave = tid >> 6;
  const int lane = tid & 63;
  const int wm = wave >> 1, wn = wave & 1;
  const int row0 = blockIdx.y * 128;
  const int col0 = blockIdx.x * 128;
  const int lr = lane >> 2;        // row within a 16-row staging chunk
  const int lc = (lane & 3) * 8;   // 8 bf16 = 16B per lane

  const int kper = Kd / SPLITK;
  const int kbeg = (SPLITK > 1) ? blockIdx.z * kper : 0;

  f32x4 acc[4][4] = {};

  for (int k0 = kbeg; k0 < kbeg + kper; k0 += 32) {
#pragma unroll
    for (int j = 0; j < 2; ++j) {
      const int rb = j * 64 + wave * 16;   // 16 rows per issue per wave
      gload_lds16(A  + (size_t)(row0 + rb + lr) * lda + k0 + lc, As + rb * 32);
      gload_lds16(Bw + (size_t)(col0 + rb + lr) * ldb + k0 + lc, Bs + rb * 32);
    }
    __syncthreads();   // drains vmcnt for global_load_lds

    const int q  = lane >> 4;
    const int mr = lane & 15;
    bf16x8 af[4], bfr[4];
#pragma unroll
    for (int t = 0; t < 4; ++t) {
      af[t]  = *reinterpret_cast<const bf16x8*>(As + (wm * 64 + t * 16 + mr) * 32 + q * 8);
      bfr[t] = *reinterpret_cast<const bf16x8*>(Bs + (wn * 64 + t * 16 + mr) * 32 + q * 8);
    }
#pragma unroll
    for (int mt = 0; mt < 4; ++mt)
#pragma unroll
      for (int nt = 0; nt < 4; ++nt)
        acc[mt][nt] = __builtin_amdgcn_mfma_f32_16x16x32_bf16(af[mt], bfr[nt], acc[mt][nt], 0, 0, 0);
    __syncthreads();
  }

  const int q  = lane >> 4;
  const int cn = lane & 15;
#pragma unroll
  for (int mt = 0; mt < 4; ++mt)
#pragma unroll
    for (int nt = 0; nt < 4; ++nt)
#pragma unroll
      for (int r = 0; r < 4; ++r) {
        const int row = row0 + wm * 64 + mt * 16 + q * 4 + r;
        const int col = col0 + wn * 64 + nt * 16 + cn;
        float v = acc[mt][nt][r];
        if (EPI == 0) {
          C[(size_t)row * ldc + col] = v;
        } else if (EPI == 1) {
          Cb[(size_t)row * ldc + col] = f2bf(v);
        } else if (EPI == 3) {
          v += bias[col];
          v = (v > 15.f) ? v : log1pf(__expf(v));   // softplus
          Cb[((size_t)row * ldc + col) * 2] = f2bf(v);  // interleaved slot 0
        } else {  // EPI == 4
          unsafeAtomicAdd(&C[(size_t)row * ldc + col], v);
        }
      }
}

// xdbl fp32 (2048x128, only cols 0..63 needed) -> xdblb bf16 (2048x64)
__global__ void xdbl_cast_k(const float* __restrict__ xdbl, u16* __restrict__ xdblb)
{
  int i = blockIdx.x * blockDim.x + threadIdx.x;   // over 2048*64/4
  int base = i * 4, row = base >> 6, col = base & 63;
  float4 v = *reinterpret_cast<const float4*>(xdbl + row * 128 + col);
  reinterpret_cast<ushort4*>(xdblb)[i] = f4bf(v);
}

// ------------------------------------------------------------------
// causal depthwise conv (k=4) + SiLU on xz half -> xcb (bf16, contiguous for
// x_proj GEMM) and dxc[2*idx+1] (interleaved copy for the scans)
// ------------------------------------------------------------------
__global__ void conv_silu_k(const u16* __restrict__ xzb, const float4* __restrict__ cw4,
                            const float* __restrict__ cb,
                            u16* __restrict__ xcb, u16* __restrict__ dxc)
{
  int idx = blockIdx.x * blockDim.x + threadIdx.x;  // over CB*CLEN*CDI
  int d   = idx & (CDI - 1);
  int row = idx >> 11;            // b*L + l
  int l   = row & (CLEN - 1);
  float4 wv = cw4[d];
  const float* wp = (const float*)&wv;
  float acc = cb[d];
#pragma unroll
  for (int i = 0; i < 4; ++i) {
    int ls = l - 3 + i;
    float v = (ls >= 0) ? bf2f(xzb[(size_t)(row - l + ls) * 4096 + d]) : 0.f;
    acc += v * wp[i];
  }
  float s = acc / (1.f + __expf(-acc));   // silu
  u16 sb = f2bf(s);
  xcb[idx] = sb;
  dxc[2 * (size_t)idx + 1] = sb;
}

// ------------------------------------------------------------------
// chunked selective scan (3 phases); P/S/Hin layout [b][chunk][n][d]
// dxc: interleaved (delta, xc) bf16 pairs, one dword per (row,d)
// ------------------------------------------------------------------
__global__ __launch_bounds__(256)
void scan_p1(const u32* __restrict__ dxc, const float* __restrict__ xdbl,
             const float* __restrict__ A_log,
             float* __restrict__ P, float* __restrict__ S)
{
  __shared__ float sB[CHL * 16];
  const int t = threadIdx.x;
  const int d = blockIdx.x * 256 + t;
  const int c = blockIdx.y, b = blockIdx.z;

  for (int i = t; i < CHL * 16; i += 256) {
    int ll = i >> 4, n = i & 15;
    sB[i] = xdbl[(size_t)(b * CLEN + c * CHL + ll) * 128 + 64 + n];
  }
  __syncthreads();

  float An[16], Pv[16], Sv[16];
#pragma unroll
  for (int n = 0; n < 16; ++n) {
    An[n] = -__expf(A_log[d * 16 + n]);
    Pv[n] = 1.f; Sv[n] = 0.f;
  }
  const size_t rbase = (size_t)(b * CLEN + c * CHL) * CDI + d;
  for (int ll = 0; ll < CHL; ++ll) {
    u32 pv = dxc[rbase + (size_t)ll * CDI];
    float dl = bf2f((u16)(pv & 0xffffu));
    float u  = bf2f((u16)(pv >> 16));
    float du = dl * u;
#pragma unroll
    for (int n = 0; n < 16; ++n) {
      float a = __expf(dl * An[n]);
      Pv[n] *= a;
      Sv[n] = a * Sv[n] + du * sB[ll * 16 + n];
    }
  }
  const size_t o = (size_t)((b * NCHUNK + c) * 16) * CDI + d;
#pragma unroll
  for (int n = 0; n < 16; ++n) {
    P[o + (size_t)n * CDI] = Pv[n];
    S[o + (size_t)n * CDI] = Sv[n];
  }
}

__global__ void scan_p2(const float* __restrict__ P, const float* __restrict__ S,
                        float* __restrict__ Hin)
{
  const int t = threadIdx.x;
  const int d = blockIdx.x * 256 + t;
  const int n = blockIdx.y, b = blockIdx.z;
  float h = 0.f;
#pragma unroll 8
  for (int c = 0; c < NCHUNK; ++c) {
    size_t o = (size_t)((b * NCHUNK + c) * 16 + n) * CDI + d;
    Hin[o] = h;
    h = P[o] * h + S[o];
  }
}

__global__ __launch_bounds__(256)
void scan_p3(const u32* __restrict__ dxc, const float* __restrict__ xdbl,
             const float* __restrict__ A_log, const float* __restrict__ Dvec,
             const u16* __restrict__ xzb, const float* __restrict__ Hin,
             u16* __restrict__ ybarb)
{
  __shared__ float sB[CHL * 16];
  __shared__ float sC[CHL * 16];
  const int t = threadIdx.x;
  const int d = blockIdx.x * 256 + t;
  const int c = blockIdx.y, b = blockIdx.z;

  for (int i = t; i < CHL * 16; i += 256) {
    int ll = i >> 4, n = i & 15;
    size_t ro = (size_t)(b * CLEN + c * CHL + ll) * 128;
    sB[i] = xdbl[ro + 64 + n];
    sC[i] = xdbl[ro + 80 + n];
  }
  __syncthreads();

  float An[16], h[16];
  const size_t ho = (size_t)((b * NCHUNK + c) * 16) * CDI + d;
#pragma unroll
  for (int n = 0; n < 16; ++n) {
    An[n] = -__expf(A_log[d * 16 + n]);
    h[n]  = Hin[ho + (size_t)n * CDI];
  }
  const float Dd = Dvec[d];
  const size_t rbase = (size_t)(b * CLEN + c * CHL);
  for (int ll = 0; ll < CHL; ++ll) {
    size_t e = (rbase + ll) * CDI + d;
    u32 pv = dxc[e];
    float dl = bf2f((u16)(pv & 0xffffu));
    float u  = bf2f((u16)(pv >> 16));
    float du = dl * u;
    float y  = 0.f;
#pragma unroll
    for (int n = 0; n < 16; ++n) {
      float a = __expf(dl * An[n]);
      h[n] = a * h[n] + du * sB[ll * 16 + n];
      y += h[n] * sC[ll * 16 + n];
    }
    y += u * Dd;
    float r = bf2f(xzb[(rbase + ll) * 4096 + CDI + d]);
    float sr = r / (1.f + __expf(-r));      // silu(res)
    ybarb[e] = f2bf(y * sr);
  }
}

// ------------------------------------------------------------------
extern "C" void kernel_launch(void* const* d_in, const int* in_sizes, int n_in,
                              void* d_out, int out_size, void* d_ws, size_t ws_size,
                              hipStream_t stream)
{
  (void)in_sizes; (void)n_in; (void)out_size; (void)ws_size;
  const float* x      = (const float*)d_in[0];
  const float* W_in   = (const float*)d_in[1];
  const float* conv_w = (const float*)d_in[2];
  const float* conv_b = (const float*)d_in[3];
  const float* W_x    = (const float*)d_in[4];
  const float* W_dt   = (const float*)d_in[5];
  const float* b_dt   = (const float*)d_in[6];
  const float* A_log  = (const float*)d_in[7];
  const float* Dvec   = (const float*)d_in[8];
  const float* W_out  = (const float*)d_in[9];
  float* out = (float*)d_out;

  // -------- workspace layout (no aliasing; total 90 MB) --------
  constexpr size_t MB = 1048576;
  char* w = (char*)d_ws;
  u16*   xzres_b = (u16*)(w + 0);                     // 16M  (alive until p3)
  u16*   xb      = (u16*)(w + 16 * MB);               // 4M
  u16*   W_inb   = (u16*)(w + 20 * MB);               // 8M
  u16*   xcb     = (u16*)(w + 28 * MB);               // 8M
  u16*   dxc     = (u16*)(w + 36 * MB);               // 16M (delta,xc pairs)
  float* xdbl    = (float*)(w + 52 * MB);             // 1M  (atomic acc)
  u16*   xdblb   = (u16*)(w + 53 * MB);               // 0.25M (2048x64)
  u16*   W_xb    = (u16*)(w + 53 * MB + 256 * 1024);  // 0.5M
  u16*   W_dtb   = (u16*)(w + 53 * MB + 768 * 1024);  // 0.25M
  float* Pb      = (float*)(w + 54 * MB);             // 8M
  float* Sb      = (float*)(w + 62 * MB);             // 8M
  float* Hin     = (float*)(w + 70 * MB);             // 8M
  u16*   ybarb   = (u16*)(w + 78 * MB);               // 8M
  u16*   W_outb  = (u16*)(w + 86 * MB);               // 4M  -> 90M total

  dim3 blk(256);
  // 0) fused casts + zero-init of atomic accumulators (out, xdbl)
  cast_all_k<<<CG_ZX / 256, blk, 0, stream>>>(x, W_in, W_dt, W_out, W_x,
                                              xb, W_inb, W_dtb, W_outb, W_xb,
                                              out, xdbl);
  // 1) in_proj (bf16 out): xzres_b[2048][4096] = xb @ W_in^T
  gemm_bt<1, 1><<<dim3(32, 16), blk, 0, stream>>>(xb, W_inb, nullptr, xzres_b, nullptr,
                                                  4096, 1024, 1024, 1024, 4096);
  // 2) conv + silu -> xcb (contiguous) + dxc slot 1
  conv_silu_k<<<(CB * CLEN * CDI) / 256, blk, 0, stream>>>(xzres_b, (const float4*)conv_w,
                                                           conv_b, xcb, dxc);
  // 3) x_proj (split-K=16, atomic): xdbl[2048][128] += xcb @ W_xb^T
  gemm_bt<4, 16><<<dim3(1, 16, 16), blk, 0, stream>>>(xcb, W_xb, xdbl, nullptr, nullptr,
                                                      128, 2048, 2048, 2048, 128);
  xdbl_cast_k<<<(CM * 64 / 4) / 256, blk, 0, stream>>>(xdbl, xdblb);
  // 4) dt_proj + softplus -> bf16 delta into dxc slot 0
  gemm_bt<3, 1><<<dim3(16, 16), blk, 0, stream>>>(xdblb, W_dtb, nullptr, dxc, b_dt,
                                                  2048, 64, 64, 64, 2048);
  // 5) selective scan (3-phase chunked, 32 chunks of 32)
  scan_p1<<<dim3(8, NCHUNK, 2), blk, 0, stream>>>((const u32*)dxc, xdbl, A_log, Pb, Sb);
  scan_p2<<<dim3(8, 16, 2), blk, 0, stream>>>(Pb, Sb, Hin);
  scan_p3<<<dim3(8, NCHUNK, 2), blk, 0, stream>>>((const u32*)dxc, xdbl, A_log, Dvec,
                                                  xzres_b, Hin, ybarb);
  // 6) out_proj (split-K=4, atomic): out[2048][1024] += ybarb @ W_out^T
  gemm_bt<4, 4><<<dim3(8, 16, 4), blk, 0, stream>>>(ybarb, W_outb, out, nullptr, nullptr,
                                                    1024, 2048, 2048, 2048, 1024);
}

// Round 6
// 250.612 us; speedup vs baseline: 1.1176x; 1.1176x over previous
//
#include <hip/hip_runtime.h>
#include <hip/hip_bf16.h>
#include <cmath>

#define DEV __device__ __forceinline__

typedef float  f32x4  __attribute__((ext_vector_type(4)));
typedef __bf16 bf16x8 __attribute__((ext_vector_type(8)));
using u16 = unsigned short;

constexpr int CB   = 2;     // batch
constexpr int CLEN = 1024;  // seq len
constexpr int CDM  = 1024;  // d_model
constexpr int CDI  = 2048;  // d_inner
constexpr int CM   = CB * CLEN;  // 2048 GEMM rows
constexpr int NCHUNK = 32;  // scan chunks
constexpr int CHL    = 32;  // chunk length

DEV u16 f2bf(float f) {
  unsigned u = __builtin_bit_cast(unsigned, f);
  unsigned r = (u + 0x7fffu + ((u >> 16) & 1u)) >> 16;  // RNE
  return (u16)r;
}
DEV float bf2f(u16 v) { return __builtin_bit_cast(float, ((unsigned)v) << 16); }

DEV ushort4 f4bf(float4 v) {
  ushort4 o;
  o.x = f2bf(v.x); o.y = f2bf(v.y); o.z = f2bf(v.z); o.w = f2bf(v.w);
  return o;
}

// ------------------------------------------------------------------
// fused cast kernel: x, W_in, W_dt, W_out (plain) + W_x (pad 96->128 rows)
// ------------------------------------------------------------------
constexpr int CG_X   = 524288;                 // 2048*1024/4
constexpr int CG_WIN = CG_X   + 1048576;       // 4096*1024/4
constexpr int CG_WDT = CG_WIN + 32768;         // 2048*64/4
constexpr int CG_WO  = CG_WDT + 524288;        // 1024*2048/4
constexpr int CG_WX  = CG_WO  + 65536;         // 128*2048/4 (padded out)

__global__ void cast_all_k(const float* __restrict__ x, const float* __restrict__ W_in,
                           const float* __restrict__ W_dt, const float* __restrict__ W_out,
                           const float* __restrict__ W_x,
                           u16* __restrict__ xb, u16* __restrict__ W_inb,
                           u16* __restrict__ W_dtb, u16* __restrict__ W_outb,
                           u16* __restrict__ W_xb)
{
  int i = blockIdx.x * blockDim.x + threadIdx.x;
  if (i < CG_X) {
    reinterpret_cast<ushort4*>(xb)[i] = f4bf(reinterpret_cast<const float4*>(x)[i]);
  } else if (i < CG_WIN) {
    int j = i - CG_X;
    reinterpret_cast<ushort4*>(W_inb)[j] = f4bf(reinterpret_cast<const float4*>(W_in)[j]);
  } else if (i < CG_WDT) {
    int j = i - CG_WIN;
    reinterpret_cast<ushort4*>(W_dtb)[j] = f4bf(reinterpret_cast<const float4*>(W_dt)[j]);
  } else if (i < CG_WO) {
    int j = i - CG_WDT;
    reinterpret_cast<ushort4*>(W_outb)[j] = f4bf(reinterpret_cast<const float4*>(W_out)[j]);
  } else {
    int j = i - CG_WO;
    int base = j * 4, row = base >> 11, col = base & 2047;
    float4 v = make_float4(0.f, 0.f, 0.f, 0.f);
    if (row < 96) v = *reinterpret_cast<const float4*>(W_x + row * 2048 + col);
    reinterpret_cast<ushort4*>(W_xb)[j] = f4bf(v);
  }
}

// ------------------------------------------------------------------
// bf16 MFMA GEMM, NT layout: C[M][N] = A[M][K] * B[N][K]^T
// 128x128 tile, BK=32, 4 waves each computing 64x64 (4x4 MFMA tiles).
// K-loop software pipeline: register prefetch of tile k+1 issued AFTER the
// second barrier, so the global loads stay in flight through the ds_read+MFMA
// phase; the next barrier's vmcnt(0) drain finds them (mostly) complete.
// EPI: 0 = fp32 store (+z*slice_stride for SPLITK); 1 = bf16 store;
//      3 = softplus(acc+bias[col]) -> bf16
// ------------------------------------------------------------------
template <int EPI, int SPLITK>
__global__ __launch_bounds__(256, 2)
void gemm_bt(const u16* __restrict__ A, const u16* __restrict__ Bw,
             float* __restrict__ C, u16* __restrict__ Cb,
             const float* __restrict__ bias,
             int Nd, int Kd, int lda, int ldb, int ldc, size_t slice_stride)
{
  __shared__ u16 As[128 * 32];
  __shared__ u16 Bs[128 * 32];
  const int tid  = threadIdx.x;
  const int wave = tid >> 6;
  const int lane = tid & 63;
  const int wm = wave >> 1, wn = wave & 1;
  const int row0 = blockIdx.y * 128;
  const int col0 = blockIdx.x * 128;
  const int lr = lane >> 2;        // row within a 16-row staging chunk
  const int lc = (lane & 3) * 8;   // 8 bf16 = 16B per lane

  const int kper = Kd / SPLITK;
  const int kbeg = (SPLITK > 1) ? blockIdx.z * kper : 0;
  const int kend = kbeg + kper;
  float* Cz = (SPLITK > 1) ? C + (size_t)blockIdx.z * slice_stride : C;

  // per-wave global staging base (rows wave*16+lr and +64)
  const u16* Ag = A  + (size_t)(row0 + wave * 16 + lr) * lda + lc;
  const u16* Bg = Bw + (size_t)(col0 + wave * 16 + lr) * ldb + lc;
  // LDS staging destinations
  u16* Al0 = As + (wave * 16 + lr) * 32 + lc;
  u16* Al1 = As + (64 + wave * 16 + lr) * 32 + lc;
  u16* Bl0 = Bs + (wave * 16 + lr) * 32 + lc;
  u16* Bl1 = Bs + (64 + wave * 16 + lr) * 32 + lc;

  // preload tile kbeg into registers
  bf16x8 pa0 = *reinterpret_cast<const bf16x8*>(Ag + kbeg);
  bf16x8 pa1 = *reinterpret_cast<const bf16x8*>(Ag + (size_t)64 * lda + kbeg);
  bf16x8 pb0 = *reinterpret_cast<const bf16x8*>(Bg + kbeg);
  bf16x8 pb1 = *reinterpret_cast<const bf16x8*>(Bg + (size_t)64 * ldb + kbeg);

  f32x4 acc[4][4] = {};
  const int q  = lane >> 4;
  const int mr = lane & 15;

  for (int k0 = kbeg; k0 < kend; k0 += 32) {
    __syncthreads();   // (a) prior iter's LDS reads done; drains old prefetch
    *reinterpret_cast<bf16x8*>(Al0) = pa0;
    *reinterpret_cast<bf16x8*>(Al1) = pa1;
    *reinterpret_cast<bf16x8*>(Bl0) = pb0;
    *reinterpret_cast<bf16x8*>(Bl1) = pb1;
    __syncthreads();   // (b) staged tile visible
    // issue prefetch of next tile; stays in flight through ds_read+MFMA
    const int k1 = (k0 + 32 < kend) ? k0 + 32 : kbeg;
    pa0 = *reinterpret_cast<const bf16x8*>(Ag + k1);
    pa1 = *reinterpret_cast<const bf16x8*>(Ag + (size_t)64 * lda + k1);
    pb0 = *reinterpret_cast<const bf16x8*>(Bg + k1);
    pb1 = *reinterpret_cast<const bf16x8*>(Bg + (size_t)64 * ldb + k1);

    bf16x8 af[4], bfr[4];
#pragma unroll
    for (int t = 0; t < 4; ++t) {
      af[t]  = *reinterpret_cast<const bf16x8*>(As + (wm * 64 + t * 16 + mr) * 32 + q * 8);
      bfr[t] = *reinterpret_cast<const bf16x8*>(Bs + (wn * 64 + t * 16 + mr) * 32 + q * 8);
    }
#pragma unroll
    for (int mt = 0; mt < 4; ++mt)
#pragma unroll
      for (int nt = 0; nt < 4; ++nt)
        acc[mt][nt] = __builtin_amdgcn_mfma_f32_16x16x32_bf16(af[mt], bfr[nt], acc[mt][nt], 0, 0, 0);
  }

  const int cn = lane & 15;
#pragma unroll
  for (int mt = 0; mt < 4; ++mt)
#pragma unroll
    for (int nt = 0; nt < 4; ++nt)
#pragma unroll
      for (int r = 0; r < 4; ++r) {
        const int row = row0 + wm * 64 + mt * 16 + q * 4 + r;
        const int col = col0 + wn * 64 + nt * 16 + cn;
        float v = acc[mt][nt][r];
        if (EPI == 3) {
          v += bias[col];
          v = (v > 15.f) ? v : log1pf(__expf(v));   // softplus
        }
        if (EPI == 0) Cz[(size_t)row * ldc + col] = v;
        else          Cb[(size_t)row * ldc + col] = f2bf(v);
      }
}

// reduce 16 split-K partials of x_proj -> fp32 xdbl + bf16 xdblb
__global__ void xdbl_reduce_k(const float* __restrict__ part,
                              float* __restrict__ xdbl, u16* __restrict__ xdblb)
{
  int i = blockIdx.x * blockDim.x + threadIdx.x;   // over 2048*128/4 groups
  float4 s = reinterpret_cast<const float4*>(part)[i];
#pragma unroll
  for (int z = 1; z < 16; ++z) {
    float4 p = reinterpret_cast<const float4*>(part + (size_t)z * CM * 128)[i];
    s.x += p.x; s.y += p.y; s.z += p.z; s.w += p.w;
  }
  reinterpret_cast<float4*>(xdbl)[i] = s;
  reinterpret_cast<ushort4*>(xdblb)[i] = f4bf(s);
}

// reduce 4 split-K partials of out_proj -> fp32 out
__global__ void out_reduce_k(const float* __restrict__ part, float* __restrict__ out)
{
  int i = blockIdx.x * blockDim.x + threadIdx.x;   // over 2048*1024/4 groups
  float4 s = reinterpret_cast<const float4*>(part)[i];
#pragma unroll
  for (int z = 1; z < 4; ++z) {
    float4 p = reinterpret_cast<const float4*>(part + (size_t)z * CM * CDM)[i];
    s.x += p.x; s.y += p.y; s.z += p.z; s.w += p.w;
  }
  reinterpret_cast<float4*>(out)[i] = s;
}

// ------------------------------------------------------------------
// causal depthwise conv (k=4) + SiLU on xz half -> xcb (bf16)
// ------------------------------------------------------------------
__global__ void conv_silu_k(const u16* __restrict__ xzb, const float4* __restrict__ cw4,
                            const float* __restrict__ cb, u16* __restrict__ xcb)
{
  int idx = blockIdx.x * blockDim.x + threadIdx.x;  // over CB*CLEN*CDI
  int d   = idx & (CDI - 1);
  int row = idx >> 11;            // b*L + l
  int l   = row & (CLEN - 1);
  float4 wv = cw4[d];
  const float* wp = (const float*)&wv;
  float acc = cb[d];
#pragma unroll
  for (int i = 0; i < 4; ++i) {
    int ls = l - 3 + i;
    float v = (ls >= 0) ? bf2f(xzb[(size_t)(row - l + ls) * 4096 + d]) : 0.f;
    acc += v * wp[i];
  }
  float s = acc / (1.f + __expf(-acc));   // silu
  xcb[idx] = f2bf(s);
}

// ------------------------------------------------------------------
// chunked selective scan (3 phases); P/S/Hin layout [b][chunk][n][d]
// ------------------------------------------------------------------
__global__ __launch_bounds__(256)
void scan_p1(const u16* __restrict__ delta_b, const u16* __restrict__ xcb,
             const float* __restrict__ xdbl, const float* __restrict__ A_log,
             float* __restrict__ P, float* __restrict__ S)
{
  __shared__ float sB[CHL * 16];
  const int t = threadIdx.x;
  const int d = blockIdx.x * 256 + t;
  const int c = blockIdx.y, b = blockIdx.z;

  for (int i = t; i < CHL * 16; i += 256) {
    int ll = i >> 4, n = i & 15;
    sB[i] = xdbl[(size_t)(b * CLEN + c * CHL + ll) * 128 + 64 + n];
  }
  __syncthreads();

  float An[16], Pv[16], Sv[16];
#pragma unroll
  for (int n = 0; n < 16; ++n) {
    An[n] = -__expf(A_log[d * 16 + n]);
    Pv[n] = 1.f; Sv[n] = 0.f;
  }
  const size_t rbase = (size_t)(b * CLEN + c * CHL) * CDI + d;
  for (int ll = 0; ll < CHL; ++ll) {
    float dl = bf2f(delta_b[rbase + (size_t)ll * CDI]);
    float u  = bf2f(xcb[rbase + (size_t)ll * CDI]);
    float du = dl * u;
#pragma unroll
    for (int n = 0; n < 16; ++n) {
      float a = __expf(dl * An[n]);
      Pv[n] *= a;
      Sv[n] = a * Sv[n] + du * sB[ll * 16 + n];
    }
  }
  const size_t o = (size_t)((b * NCHUNK + c) * 16) * CDI + d;
#pragma unroll
  for (int n = 0; n < 16; ++n) {
    P[o + (size_t)n * CDI] = Pv[n];
    S[o + (size_t)n * CDI] = Sv[n];
  }
}

__global__ void scan_p2(const float* __restrict__ P, const float* __restrict__ S,
                        float* __restrict__ Hin)
{
  const int t = threadIdx.x;
  const int d = blockIdx.x * 256 + t;
  const int n = blockIdx.y, b = blockIdx.z;
  float h = 0.f;
#pragma unroll 8
  for (int c = 0; c < NCHUNK; ++c) {
    size_t o = (size_t)((b * NCHUNK + c) * 16 + n) * CDI + d;
    Hin[o] = h;
    h = P[o] * h + S[o];
  }
}

__global__ __launch_bounds__(256)
void scan_p3(const u16* __restrict__ delta_b, const u16* __restrict__ xcb,
             const float* __restrict__ xdbl, const float* __restrict__ A_log,
             const float* __restrict__ Dvec, const u16* __restrict__ xzb,
             const float* __restrict__ Hin, u16* __restrict__ ybarb)
{
  __shared__ float sB[CHL * 16];
  __shared__ float sC[CHL * 16];
  const int t = threadIdx.x;
  const int d = blockIdx.x * 256 + t;
  const int c = blockIdx.y, b = blockIdx.z;

  for (int i = t; i < CHL * 16; i += 256) {
    int ll = i >> 4, n = i & 15;
    size_t ro = (size_t)(b * CLEN + c * CHL + ll) * 128;
    sB[i] = xdbl[ro + 64 + n];
    sC[i] = xdbl[ro + 80 + n];
  }
  __syncthreads();

  float An[16], h[16];
  const size_t ho = (size_t)((b * NCHUNK + c) * 16) * CDI + d;
#pragma unroll
  for (int n = 0; n < 16; ++n) {
    An[n] = -__expf(A_log[d * 16 + n]);
    h[n]  = Hin[ho + (size_t)n * CDI];
  }
  const float Dd = Dvec[d];
  const size_t rbase = (size_t)(b * CLEN + c * CHL);
  for (int ll = 0; ll < CHL; ++ll) {
    size_t e = (rbase + ll) * CDI + d;
    float dl = bf2f(delta_b[e]);
    float u  = bf2f(xcb[e]);
    float du = dl * u;
    float y  = 0.f;
#pragma unroll
    for (int n = 0; n < 16; ++n) {
      float a = __expf(dl * An[n]);
      h[n] = a * h[n] + du * sB[ll * 16 + n];
      y += h[n] * sC[ll * 16 + n];
    }
    y += u * Dd;
    float r = bf2f(xzb[(rbase + ll) * 4096 + CDI + d]);
    float sr = r / (1.f + __expf(-r));      // silu(res)
    ybarb[e] = f2bf(y * sr);
  }
}

// ------------------------------------------------------------------
extern "C" void kernel_launch(void* const* d_in, const int* in_sizes, int n_in,
                              void* d_out, int out_size, void* d_ws, size_t ws_size,
                              hipStream_t stream)
{
  (void)in_sizes; (void)n_in; (void)out_size; (void)ws_size;
  const float* x      = (const float*)d_in[0];
  const float* W_in   = (const float*)d_in[1];
  const float* conv_w = (const float*)d_in[2];
  const float* conv_b = (const float*)d_in[3];
  const float* W_x    = (const float*)d_in[4];
  const float* W_dt   = (const float*)d_in[5];
  const float* b_dt   = (const float*)d_in[6];
  const float* A_log  = (const float*)d_in[7];
  const float* Dvec   = (const float*)d_in[8];
  const float* W_out  = (const float*)d_in[9];
  float* out = (float*)d_out;

  // -------- workspace layout (no aliasing; total 130 MB, ws is 256 MB) ----
  constexpr size_t MB = 1048576;
  char* w = (char*)d_ws;
  u16*   xzres_b = (u16*)(w + 0);                     // 16M (alive until p3)
  u16*   xb      = (u16*)(w + 16 * MB);               // 4M
  u16*   W_inb   = (u16*)(w + 20 * MB);               // 8M
  u16*   xcb     = (u16*)(w + 28 * MB);               // 8M
  u16*   delta_b = (u16*)(w + 36 * MB);               // 8M
  float* xpart   = (float*)(w + 44 * MB);             // 16M (16 slices x 1M)
  float* xdbl    = (float*)(w + 60 * MB);             // 1M
  u16*   xdblb   = (u16*)(w + 61 * MB);               // 0.5M (2048x128)
  u16*   W_xb    = (u16*)(w + 61 * MB + 512 * 1024);  // 0.5M
  u16*   W_dtb   = (u16*)(w + 62 * MB);               // 0.25M
  float* Pb      = (float*)(w + 63 * MB);             // 8M
  float* Sb      = (float*)(w + 71 * MB);             // 8M
  float* Hin     = (float*)(w + 79 * MB);             // 8M
  u16*   ybarb   = (u16*)(w + 87 * MB);               // 8M
  u16*   W_outb  = (u16*)(w + 95 * MB);               // 4M
  float* opart   = (float*)(w + 99 * MB);             // 32M -> 131M total

  dim3 blk(256);
  // 0) fused casts
  cast_all_k<<<CG_WX / 256, blk, 0, stream>>>(x, W_in, W_dt, W_out, W_x,
                                              xb, W_inb, W_dtb, W_outb, W_xb);
  // 1) in_proj (bf16 out): xzres_b[2048][4096] = xb @ W_in^T
  gemm_bt<1, 1><<<dim3(32, 16), blk, 0, stream>>>(xb, W_inb, nullptr, xzres_b, nullptr,
                                                  4096, 1024, 1024, 1024, 4096, 0);
  // 2) conv + silu -> xcb
  conv_silu_k<<<(CB * CLEN * CDI) / 256, blk, 0, stream>>>(xzres_b, (const float4*)conv_w,
                                                           conv_b, xcb);
  // 3) x_proj (split-K=16): xpart[z][2048][128] = xcb @ W_xb^T, then reduce
  gemm_bt<0, 16><<<dim3(1, 16, 16), blk, 0, stream>>>(xcb, W_xb, xpart, nullptr, nullptr,
                                                      128, 2048, 2048, 2048, 128,
                                                      (size_t)CM * 128);
  xdbl_reduce_k<<<(CM * 128 / 4) / 256, blk, 0, stream>>>(xpart, xdbl, xdblb);
  // 4) dt_proj + softplus -> bf16 delta
  gemm_bt<3, 1><<<dim3(16, 16), blk, 0, stream>>>(xdblb, W_dtb, nullptr, delta_b, b_dt,
                                                  2048, 64, 128, 64, 2048, 0);
  // 5) selective scan (3-phase chunked, 32 chunks of 32)
  scan_p1<<<dim3(8, NCHUNK, 2), blk, 0, stream>>>(delta_b, xcb, xdbl, A_log, Pb, Sb);
  scan_p2<<<dim3(8, 16, 2), blk, 0, stream>>>(Pb, Sb, Hin);
  scan_p3<<<dim3(8, NCHUNK, 2), blk, 0, stream>>>(delta_b, xcb, xdbl, A_log, Dvec,
                                                  xzres_b, Hin, ybarb);
  // 6) out_proj (split-K=4): opart[z][2048][1024] = ybarb @ W_out^T, then reduce
  gemm_bt<0, 4><<<dim3(8, 16, 4), blk, 0, stream>>>(ybarb, W_outb, opart, nullptr, nullptr,
                                                    1024, 2048, 2048, 2048, 1024,
                                                    (size_t)CM * CDM);
  out_reduce_k<<<(CM * CDM / 4) / 256, blk, 0, stream>>>(opart, out);
}